// Round 14
// baseline (921.686 us; speedup 1.0000x reference)
//
#include <hip/hip_runtime.h>
#include <hip/hip_bf16.h>
#include <math.h>

// ---------------------------------------------------------------------------
// GCN part-seg pipeline.
// R14: XCD-PINNED sliced aggregation: blocks read their physical XCD id via
//      s_getreg(HW_REG_XCC_ID) and drain a per-XCD queue of node-slabs for
//      their own 64B feature slice -> per-XCD gather working set 3.2MB, L2-
//      resident by construction. Work-stealing sweep keeps it correct even if
//      the id read fails. Edges packed as int2. GEMMs/MLP as R13.
// ---------------------------------------------------------------------------

typedef __attribute__((ext_vector_type(8))) short short8;     // 8 bf16
typedef __attribute__((ext_vector_type(8))) _Float16 half8;   // 8 fp16
typedef __attribute__((ext_vector_type(4))) float floatx4;    // 4 fp32

// s_getreg(HW_REG_XCC_ID): id=20, offset=0, size=4 -> imm = 20 | (3<<11)
#define XCC_ID_IMM 6164

__device__ __forceinline__ unsigned short bf16h(float f) {
    unsigned int u = __float_as_uint(f);
    u += 0x7fff + ((u >> 16) & 1);          // round-to-nearest-even
    return (unsigned short)(u >> 16);
}
__device__ __forceinline__ float bf16f(unsigned short h) {
    return __uint_as_float(((unsigned int)h) << 16);
}

__device__ __forceinline__ void gld_lds16(unsigned short* lds, const unsigned short* g) {
    __builtin_amdgcn_global_load_lds(
        (const __attribute__((address_space(1))) unsigned int*)g,
        (__attribute__((address_space(3))) unsigned int*)lds, 16, 0, 0);
}

// ---------------- degree / CSR build ----------------

__global__ void hist_kernel(const int* __restrict__ dst, int* __restrict__ counts, int e) {
    int g = blockIdx.x * blockDim.x + threadIdx.x;
    if (g < e) atomicAdd(&counts[dst[g]], 1);
}

__global__ void scan1_kernel(const int* __restrict__ counts, int* __restrict__ bsum, int n) {
    __shared__ int buf[256];
    int i = blockIdx.x * 256 + threadIdx.x;
    buf[threadIdx.x] = (i < n) ? counts[i] : 0;
    __syncthreads();
    for (int off = 128; off > 0; off >>= 1) {
        if (threadIdx.x < off) buf[threadIdx.x] += buf[threadIdx.x + off];
        __syncthreads();
    }
    if (threadIdx.x == 0) bsum[blockIdx.x] = buf[0];
}

__global__ void scan2_kernel(const int* __restrict__ bsum, int* __restrict__ bsumx,
                             int* __restrict__ offsets, int nb, int n) {
    __shared__ int buf[256];
    int tid = threadIdx.x;
    int v = (tid < nb) ? bsum[tid] : 0;
    buf[tid] = v;
    __syncthreads();
    for (int off = 1; off < 256; off <<= 1) {
        int t = (tid >= off) ? buf[tid - off] : 0;
        __syncthreads();
        buf[tid] += t;
        __syncthreads();
    }
    if (tid < nb) bsumx[tid] = buf[tid] - v;       // exclusive
    if (tid == 255) offsets[n] = buf[255];          // total
}

__global__ void scan3_kernel(const int* __restrict__ counts, const int* __restrict__ bsumx,
                             int* __restrict__ offsets, int* __restrict__ cursor,
                             float* __restrict__ dinv, int n) {
    __shared__ int buf[256];
    int tid = threadIdx.x;
    int i = blockIdx.x * 256 + tid;
    int c = (i < n) ? counts[i] : 0;
    buf[tid] = c;
    __syncthreads();
    for (int off = 1; off < 256; off <<= 1) {
        int t = (tid >= off) ? buf[tid - off] : 0;
        __syncthreads();
        buf[tid] += t;
        __syncthreads();
    }
    if (i < n) {
        int excl = bsumx[blockIdx.x] + buf[tid] - c;
        offsets[i] = excl;
        cursor[i] = excl;
        dinv[i] = rsqrtf((float)c + 1.0f);
    }
}

__global__ void fill_kernel(const int* __restrict__ src, const int* __restrict__ dst,
                            const float* __restrict__ dinv, int* __restrict__ cursor,
                            int2* __restrict__ edges, int e) {
    int g = blockIdx.x * blockDim.x + threadIdx.x;
    if (g >= e) return;
    int s = src[g], d = dst[g];
    int pos = atomicAdd(&cursor[d], 1);
    edges[pos] = make_int2(s, __float_as_int(dinv[s] * dinv[d]));
}

// ---------------- fused weight prep ----------------
// f16 GEMMs: W[K][N] fp32 -> Btf[N][K] fp16 (transposed).
// GCN3 (emulated): g3w padded -> Bt3[N][2K] bf16 = [Bh;Bl].

__global__ void prepw_kernel(const float* __restrict__ g1w, const float* __restrict__ g2w,
                             const float* __restrict__ g3w, const float* __restrict__ w3,
                             _Float16* __restrict__ Bt1f,
                             _Float16* __restrict__ Bt2f,
                             unsigned short* __restrict__ Bt3,
                             _Float16* __restrict__ Bt0f) {
    int gid = blockIdx.x * blockDim.x + threadIdx.x;
    if (gid < 32768) {                       // g1: K=128, N=256
        int k = gid >> 8, n = gid & 255;
        Bt1f[(size_t)n * 128 + k] = (_Float16)g1w[gid];
    } else if (gid < 32768 + 131072) {       // g2: K=256, N=512
        int idx = gid - 32768;
        int k = idx >> 9, n = idx & 511;
        Bt2f[(size_t)n * 256 + k] = (_Float16)g2w[idx];
    } else if (gid < 32768 + 131072 + 32768) { // g3 padded: K=512, N=64 (bf16 hi/lo)
        int idx = gid - 32768 - 131072;
        int k = idx >> 6, c = idx & 63;
        float w = (c < 50) ? g3w[k * 50 + c] : 0.0f;
        unsigned short h = bf16h(w);
        unsigned short l = bf16h(w - bf16f(h));
        size_t base = (size_t)c * 1024;
        Bt3[base + k]       = h;
        Bt3[base + 512 + k] = l;
    } else if (gid < 32768 + 131072 + 32768 + 8192) { // w3: K=64, N=128
        int idx = gid - 32768 - 131072 - 32768;
        int k = idx >> 7, n = idx & 127;
        Bt0f[(size_t)n * 64 + k] = (_Float16)w3[idx];
    }
}

// ---------------- fused MLP layers 1+2: x[N,3] -> h2 fp16 [N,64] ------------

__global__ __launch_bounds__(256) void mlp12_kernel(
        const float* __restrict__ x,
        const float* __restrict__ w1, const float* __restrict__ b1,
        const float* __restrict__ w2, const float* __restrict__ b2,
        _Float16* __restrict__ H2f, int n) {
    __shared__ float sw1[96], sb1[32], sw2[2048], sb2[64];
    int tid = threadIdx.x;
    if (tid < 96) sw1[tid] = w1[tid];
    if (tid < 32) sb1[tid] = b1[tid];
    if (tid < 64) sb2[tid] = b2[tid];
    for (int i = tid; i < 2048; i += 256) sw2[i] = w2[i];
    __syncthreads();

    int node = blockIdx.x * 256 + tid;
    if (node >= n) return;
    float x0 = x[node * 3 + 0], x1 = x[node * 3 + 1], x2 = x[node * 3 + 2];
    float h1[32];
#pragma unroll
    for (int j = 0; j < 32; j++)
        h1[j] = fmaxf(sb1[j] + x0 * sw1[j] + x1 * sw1[32 + j] + x2 * sw1[64 + j], 0.0f);

    float acc[64];
#pragma unroll
    for (int j = 0; j < 64; j++) acc[j] = sb2[j];
    for (int k = 0; k < 32; k++) {
        float hk = h1[k];
#pragma unroll
        for (int j4 = 0; j4 < 16; j4++) {
            float4 w = *(const float4*)&sw2[k * 64 + j4 * 4];
            acc[j4 * 4 + 0] = fmaf(hk, w.x, acc[j4 * 4 + 0]);
            acc[j4 * 4 + 1] = fmaf(hk, w.y, acc[j4 * 4 + 1]);
            acc[j4 * 4 + 2] = fmaf(hk, w.z, acc[j4 * 4 + 2]);
            acc[j4 * 4 + 3] = fmaf(hk, w.w, acc[j4 * 4 + 3]);
        }
    }
#pragma unroll
    for (int j8 = 0; j8 < 8; j8++) {
        half8 o;
#pragma unroll
        for (int t = 0; t < 8; t++)
            o[t] = (_Float16)fmaxf(acc[j8 * 8 + t], 0.0f);
        *reinterpret_cast<half8*>(&H2f[(size_t)node * 64 + j8 * 8]) = o;
    }
}

// ---------------- native f16 MFMA GEMM --------------------------------------

template<int BM, int BN, int WAVES, int WGR, int WGC, int WRF, int WCF, int SWIZCOLS>
__global__ __launch_bounds__(WAVES * 64) void gemm_f16_kernel(
        const _Float16* __restrict__ A, const _Float16* __restrict__ Btf,
        const float* __restrict__ bias, _Float16* __restrict__ C,
        int M, int K, int N) {
    static_assert(WGR * WRF * 16 == BM, "row cover");
    static_assert(WGC * WCF * 16 == BN, "col cover");
    static_assert(WGR * WGC == WAVES, "wave grid");
    constexpr int AUNITS = BM / 16, BUNITS = BN / 16;
    static_assert(AUNITS % WAVES == 0 && BUNITS % WAVES == 0, "staging split");
    __shared__ __align__(16) unsigned short Ash[BM * 32];
    __shared__ __align__(16) unsigned short Bsh[BN * 32];

    int bm, bn;
    if (SWIZCOLS > 0) {
        constexpr int CSH = (SWIZCOLS == 4) ? 2 : 1;
        int b = blockIdx.x;
        int col = (b >> 3) & (SWIZCOLS - 1);
        int row = ((b >> (3 + CSH)) << 3) | (b & 7);
        bm = row * BM;
        bn = col * BN;
        if (bm >= M) return;             // padded row block (uniform exit)
    } else {
        bm = blockIdx.y * BM;
        bn = blockIdx.x * BN;
    }

    const int tid  = threadIdx.x;
    const int lane = tid & 63;
    const int wave = tid >> 6;
    const int wr0 = (wave / WGC) * (WRF * 16);
    const int wc0 = (wave % WGC) * (WCF * 16);
    const int lr   = lane & 15;
    const int quad = lane >> 4;
    const int arow = lane >> 2;          // row within 16-row group
    const int acol = (lane & 3) * 8;     // halves within 32-half row

    floatx4 acc[WRF][WCF];
#pragma unroll
    for (int i = 0; i < WRF; i++)
#pragma unroll
        for (int j = 0; j < WCF; j++) acc[i][j] = floatx4{0.f, 0.f, 0.f, 0.f};

    for (int k0 = 0; k0 < K; k0 += 32) {
#pragma unroll
        for (int u = 0; u < AUNITS / WAVES; u++) {
            int grp = wave + u * WAVES;
            int gm = bm + grp * 16 + arow;
            if (gm >= M) gm = M - 1;     // clamp: garbage rows discarded at store
            gld_lds16(&Ash[grp * 512],
                      (const unsigned short*)(A + (size_t)gm * K + k0 + acol));
        }
#pragma unroll
        for (int u = 0; u < BUNITS / WAVES; u++) {
            int grp = wave + u * WAVES;
            int gr = bn + grp * 16 + arow;
            gld_lds16(&Bsh[grp * 512],
                      (const unsigned short*)(Btf + (size_t)gr * K + k0 + acol));
        }
        __syncthreads();

        half8 af[WRF], bf[WCF];
#pragma unroll
        for (int i = 0; i < WRF; i++)
            af[i] = *reinterpret_cast<const half8*>(
                &Ash[(wr0 + i * 16 + lr) * 32 + quad * 8]);
#pragma unroll
        for (int j = 0; j < WCF; j++)
            bf[j] = *reinterpret_cast<const half8*>(
                &Bsh[(wc0 + j * 16 + lr) * 32 + quad * 8]);
#pragma unroll
        for (int i = 0; i < WRF; i++)
#pragma unroll
            for (int j = 0; j < WCF; j++)
                acc[i][j] = __builtin_amdgcn_mfma_f32_16x16x32_f16(
                    af[i], bf[j], acc[i][j], 0, 0, 0);
        __syncthreads();
    }

    // epilogue: C/D layout col=lane&15, row=quad*4+reg (m89-verified)
#pragma unroll
    for (int i = 0; i < WRF; i++) {
#pragma unroll
        for (int j = 0; j < WCF; j++) {
            int gc = bn + wc0 + j * 16 + lr;
#pragma unroll
            for (int reg = 0; reg < 4; reg++) {
                int gr = bm + wr0 + i * 16 + quad * 4 + reg;
                if (gr >= M) continue;
                float v = fmaxf(acc[i][j][reg] + bias[gc], 0.0f);
                C[(size_t)gr * N + gc] = (_Float16)v;
            }
        }
    }
}

// ---------------- emulated GEMM for GCN3 (logit layer) ----------------------

template<int BM, int BN, int WAVES, int WGR, int WGC, int WRF, int WCF>
__global__ __launch_bounds__(WAVES * 64) void gemm_emul_kernel(
        const _Float16* __restrict__ Af, const unsigned short* __restrict__ Bt,
        _Float16* __restrict__ C, int M, int K, int N) {
    static_assert(WGR * WRF * 16 == BM, "row cover");
    static_assert(WGC * WCF * 16 == BN, "col cover");
    static_assert(WGR * WGC == WAVES, "wave grid");
    constexpr int AUNITS = BM / 16, BUNITS = BN / 8;
    static_assert(AUNITS % WAVES == 0 && BUNITS % WAVES == 0, "staging split");
    __shared__ __align__(16) unsigned short Ash[BM * 32];
    __shared__ __align__(16) unsigned short Bsh[BN * 32];
    __shared__ __align__(16) unsigned short Bsl[BN * 32];

    const int bm = blockIdx.y * BM;
    const int bn = blockIdx.x * BN;
    const int tid  = threadIdx.x;
    const int lane = tid & 63;
    const int wave = tid >> 6;
    const int K2 = 2 * K;
    const int wr0 = (wave / WGC) * (WRF * 16);
    const int wc0 = (wave % WGC) * (WCF * 16);
    const int lr   = lane & 15;
    const int quad = lane >> 4;
    const int arow = lane >> 2;
    const int acol = (lane & 3) * 8;

    floatx4 acc[WRF][WCF];
#pragma unroll
    for (int i = 0; i < WRF; i++)
#pragma unroll
        for (int j = 0; j < WCF; j++) acc[i][j] = floatx4{0.f, 0.f, 0.f, 0.f};

    for (int k0 = 0; k0 < K; k0 += 32) {
#pragma unroll
        for (int u = 0; u < AUNITS / WAVES; u++) {
            int grp = wave + u * WAVES;
            int gm = bm + grp * 16 + arow;
            if (gm >= M) gm = M - 1;
            gld_lds16(&Ash[grp * 512],
                      (const unsigned short*)(Af + (size_t)gm * K + k0 + acol));
        }
#pragma unroll
        for (int u = 0; u < BUNITS / WAVES; u++) {
            int unit = wave + u * WAVES;
            int grp = unit >> 1, pl = unit & 1;
            int gr = bn + grp * 16 + arow;
            size_t go = (size_t)gr * K2 + k0 + acol + (pl ? K : 0);
            if (pl) gld_lds16(&Bsl[grp * 512], Bt + go);
            else    gld_lds16(&Bsh[grp * 512], Bt + go);
        }
        __syncthreads();

        short8 ahf[WRF], alf[WRF], bhf[WCF], blf[WCF];
#pragma unroll
        for (int i = 0; i < WRF; i++) {
            half8 av = *reinterpret_cast<const half8*>(
                &Ash[(wr0 + i * 16 + lr) * 32 + quad * 8]);
#pragma unroll
            for (int t = 0; t < 8; t++) {
                float f = (float)av[t];
                unsigned short h = bf16h(f);
                ahf[i][t] = (short)h;
                alf[i][t] = (short)bf16h(f - bf16f(h));
            }
        }
#pragma unroll
        for (int j = 0; j < WCF; j++) {
            int ro = (wc0 + j * 16 + lr) * 32 + quad * 8;
            bhf[j] = *reinterpret_cast<const short8*>(&Bsh[ro]);
            blf[j] = *reinterpret_cast<const short8*>(&Bsl[ro]);
        }
#pragma unroll
        for (int i = 0; i < WRF; i++)
#pragma unroll
            for (int j = 0; j < WCF; j++) {
                acc[i][j] = __builtin_amdgcn_mfma_f32_16x16x32_bf16(
                    ahf[i], bhf[j], acc[i][j], 0, 0, 0);
                acc[i][j] = __builtin_amdgcn_mfma_f32_16x16x32_bf16(
                    ahf[i], blf[j], acc[i][j], 0, 0, 0);
                acc[i][j] = __builtin_amdgcn_mfma_f32_16x16x32_bf16(
                    alf[i], bhf[j], acc[i][j], 0, 0, 0);
            }
        __syncthreads();
    }

#pragma unroll
    for (int i = 0; i < WRF; i++) {
#pragma unroll
        for (int j = 0; j < WCF; j++) {
            int gc = bn + wc0 + j * 16 + lr;
#pragma unroll
            for (int reg = 0; reg < 4; reg++) {
                int gr = bm + wr0 + i * 16 + quad * 4 + reg;
                if (gr >= M) continue;
                C[(size_t)gr * N + gc] = (_Float16)acc[i][j][reg];
            }
        }
    }
}

// ---------------- XCD-pinned sliced aggregation ------------------------------
// Each block reads its physical XCD id and drains the per-XCD queue of node
// slabs, gathering only slice q = queue-id (SF features, 64B at F=256). Per-
// XCD table working set = n*SF*2 bytes (3.2MB @ F=256) -> L2-resident.
// Work-stealing sweep over all 8 queues guarantees full coverage regardless
// of the id read. Queue atomics give exactly-once processing.

template<int F>
__global__ __launch_bounds__(256) void agg_slice_kernel(
        const _Float16* __restrict__ table,
        const int* __restrict__ offsets,
        const int2* __restrict__ edges,
        const float* __restrict__ dinv,
        _Float16* __restrict__ Aout,
        int* __restrict__ qheads, int n) {
    constexpr int SF  = F / 8;           // features per slice
    constexpr int LPN = SF / 8;          // lanes per node (8 fp16 = 16B each)
    constexpr int NPB = 256 / LPN;       // nodes per slab
    const int nslabs = (n + NPB - 1) / NPB;

    __shared__ int sx, sslab;
    const int tid = threadIdx.x;
    if (tid == 0) sx = __builtin_amdgcn_s_getreg(XCC_ID_IMM) & 7;
    __syncthreads();
    const int myx = sx;
    const int sub = tid & (LPN - 1);
    const int nid = tid / LPN;

    for (int t = 0; t < 8; t++) {
        int q = (myx + t) & 7;
        const int f0 = q * SF + sub * 8;
        while (true) {
            if (tid == 0) sslab = atomicAdd(&qheads[q], 1);
            __syncthreads();
            int slab = sslab;
            __syncthreads();
            if (slab >= nslabs) break;
            int node = slab * NPB + nid;
            if (node < n) {
                float a0[8], a1[8];
#pragma unroll
                for (int i = 0; i < 8; i++) { a0[i] = 0.f; a1[i] = 0.f; }
                int beg = offsets[node], end = offsets[node + 1];
                int e = beg;
                for (; e + 4 <= end; e += 4) {
                    int2 E0 = edges[e + 0], E1 = edges[e + 1];
                    int2 E2 = edges[e + 2], E3 = edges[e + 3];
                    half8 r0 = *reinterpret_cast<const half8*>(
                        table + (size_t)E0.x * F + f0);
                    half8 r1 = *reinterpret_cast<const half8*>(
                        table + (size_t)E1.x * F + f0);
                    half8 r2 = *reinterpret_cast<const half8*>(
                        table + (size_t)E2.x * F + f0);
                    half8 r3 = *reinterpret_cast<const half8*>(
                        table + (size_t)E3.x * F + f0);
                    float w0 = __int_as_float(E0.y), w1 = __int_as_float(E1.y);
                    float w2 = __int_as_float(E2.y), w3 = __int_as_float(E3.y);
#pragma unroll
                    for (int i = 0; i < 8; i++) {
                        a0[i] = fmaf((float)r0[i], w0, a0[i]);
                        a1[i] = fmaf((float)r1[i], w1, a1[i]);
                        a0[i] = fmaf((float)r2[i], w2, a0[i]);
                        a1[i] = fmaf((float)r3[i], w3, a1[i]);
                    }
                }
                for (; e < end; ++e) {
                    int2 E0 = edges[e];
                    half8 r0 = *reinterpret_cast<const half8*>(
                        table + (size_t)E0.x * F + f0);
                    float w0 = __int_as_float(E0.y);
#pragma unroll
                    for (int i = 0; i < 8; i++)
                        a0[i] = fmaf((float)r0[i], w0, a0[i]);
                }
                float dv = dinv[node];
                float sw = dv * dv;
                half8 rs = *reinterpret_cast<const half8*>(
                    table + (size_t)node * F + f0);
                half8 o;
#pragma unroll
                for (int i = 0; i < 8; i++)
                    o[i] = (_Float16)fmaf((float)rs[i], sw, a0[i] + a1[i]);
                *reinterpret_cast<half8*>(&Aout[(size_t)node * F + f0]) = o;
            }
        }
    }
}

// ---------------- fused final aggregation + softmax: one wave per node ------
// z[N,64] fp16 (cols 50..63 zero); out[N,50] = softmax(AGG(z)+bias).

__global__ void agg50_softmax_kernel(const _Float16* __restrict__ z,
                                     const int* __restrict__ offsets,
                                     const int2* __restrict__ edges,
                                     const float* __restrict__ dinv,
                                     const float* __restrict__ bias,
                                     float* __restrict__ out, int n) {
    int node = blockIdx.x * 4 + (threadIdx.x >> 6);
    int lane = threadIdx.x & 63;
    if (node >= n) return;

    float a0 = 0.f, a1 = 0.f, a2 = 0.f, a3 = 0.f;
    int beg = offsets[node], end = offsets[node + 1];
    int e = beg;
    for (; e + 4 <= end; e += 4) {
        int2 E0 = edges[e + 0], E1 = edges[e + 1];
        int2 E2 = edges[e + 2], E3 = edges[e + 3];
        float r0 = (float)z[(size_t)E0.x * 64 + lane];
        float r1 = (float)z[(size_t)E1.x * 64 + lane];
        float r2 = (float)z[(size_t)E2.x * 64 + lane];
        float r3 = (float)z[(size_t)E3.x * 64 + lane];
        a0 = fmaf(r0, __int_as_float(E0.y), a0);
        a1 = fmaf(r1, __int_as_float(E1.y), a1);
        a2 = fmaf(r2, __int_as_float(E2.y), a2);
        a3 = fmaf(r3, __int_as_float(E3.y), a3);
    }
    for (; e < end; ++e) {
        int2 E0 = edges[e];
        a0 = fmaf((float)z[(size_t)E0.x * 64 + lane], __int_as_float(E0.y), a0);
    }

    float dv = dinv[node];
    float a = fmaf((float)z[(size_t)node * 64 + lane], dv * dv,
                   (a0 + a1) + (a2 + a3));

    float v = (lane < 50) ? a + bias[lane] : -INFINITY;
    float m = v;
#pragma unroll
    for (int off = 32; off > 0; off >>= 1) m = fmaxf(m, __shfl_xor(m, off));
    float ex = (lane < 50) ? expf(v - m) : 0.0f;
    float s = ex;
#pragma unroll
    for (int off = 32; off > 0; off >>= 1) s += __shfl_xor(s, off);
    if (lane < 50) out[(size_t)node * 50 + lane] = ex / s;
}

// ---------------------------------------------------------------------------

extern "C" void kernel_launch(void* const* d_in, const int* in_sizes, int n_in,
                              void* d_out, int out_size, void* d_ws, size_t ws_size,
                              hipStream_t stream) {
    const float* x    = (const float*)d_in[0];
    const int*   ei   = (const int*)  d_in[1];
    const float* w1   = (const float*)d_in[2];
    const float* b1   = (const float*)d_in[3];
    const float* w2   = (const float*)d_in[4];
    const float* b2   = (const float*)d_in[5];
    const float* w3   = (const float*)d_in[6];
    const float* b3   = (const float*)d_in[7];
    const float* g1w  = (const float*)d_in[8];
    const float* g1b  = (const float*)d_in[9];
    const float* g2w  = (const float*)d_in[10];
    const float* g2b  = (const float*)d_in[11];
    const float* g3w  = (const float*)d_in[12];
    const float* g3b  = (const float*)d_in[13];
    float* out = (float*)d_out;

    const int N = in_sizes[0] / 3;      // 50000
    const int E = in_sizes[1] / 2;      // 800000
    const int* src = ei;
    const int* dst = ei + E;
    const int NB = (N + 255) / 256;     // 196

    // ---- workspace arena with liveness-based region reuse ----
    char* ws = (char*)d_ws;
    size_t off = 0;
    auto alloc = [&](size_t bytes) -> char* {
        char* p = ws + off;
        off = (off + bytes + 255) & ~(size_t)255;
        return p;
    };
    int*   counts  = (int*)  alloc((size_t)N * 4);
    int*   qheads  = (int*)  alloc((size_t)16 * 4);
    int*   offsets = (int*)  alloc((size_t)(N + 1) * 4);
    int*   cursor  = (int*)  alloc((size_t)N * 4);
    float* dinv    = (float*)alloc((size_t)N * 4);
    int*   bsum    = (int*)  alloc((size_t)256 * 4);
    int*   bsumx   = (int*)  alloc((size_t)256 * 4);
    int2*  edges   = (int2*) alloc((size_t)E * 8);
    _Float16* Bt1f = (_Float16*)alloc((size_t)256 * 128 * 2);
    _Float16* Bt2f = (_Float16*)alloc((size_t)512 * 256 * 2);
    unsigned short* Bt3 = (unsigned short*)alloc((size_t)64 * 1024 * 2);
    _Float16* Bt0f = (_Float16*)alloc((size_t)128 * 64 * 2);
    char* R1 = alloc((size_t)N * 256 * 4);   // 51.2 MB
    char* R2 = alloc((size_t)N * 256 * 4);   // 51.2 MB
    char* R3 = alloc((size_t)N * 512 * 2);   // 51.2 MB (A512 fp16)
    (void)ws_size;

    // R1 phase 1: S128f [N,128] fp16 | A128f [N,128] fp16   phase 2: A256f
    _Float16*       S128f = (_Float16*)R1;
    _Float16*       A128f = (_Float16*)(R1 + (size_t)N * 128 * 2);
    _Float16*       A256f = (_Float16*)R1;
    // R2 phase 1: H2f [N,64] fp16   phase 2: G1f [N,256] fp16   phase 3: zbuf
    _Float16*       H2f  = (_Float16*)R2;
    _Float16*       G1f  = (_Float16*)R2;
    _Float16*       zbuf = (_Float16*)R2;
    // R3: A512f fp16 [N,512]
    _Float16*       A512f = (_Float16*)R3;

    // ---- degree + CSR + weight prep ----
    hipMemsetAsync(counts, 0, (size_t)N * 4, stream);
    hipMemsetAsync(qheads, 0, 64, stream);
    hist_kernel<<<(E + 255) / 256, 256, 0, stream>>>(dst, counts, E);
    scan1_kernel<<<NB, 256, 0, stream>>>(counts, bsum, N);
    scan2_kernel<<<1, 256, 0, stream>>>(bsum, bsumx, offsets, NB, N);
    scan3_kernel<<<NB, 256, 0, stream>>>(counts, bsumx, offsets, cursor, dinv, N);
    fill_kernel<<<(E + 255) / 256, 256, 0, stream>>>(src, dst, dinv, cursor, edges, E);
    prepw_kernel<<<(204800 + 255) / 256, 256, 0, stream>>>(
        g1w, g2w, g3w, w3, Bt1f, Bt2f, Bt3, Bt0f);

    const int MB = (N + 127) / 128;     // 391 row-blocks (BM=128)
    const int MB8 = (MB + 7) & ~7;      // 392 (pad to 8 for swizzle)
    const int MB64 = (N + 63) / 64;     // 782 row-blocks (BM=64)

    // ---- MLP: x -> h2 fp16 (fused), h2 -> h3 fp16 (f16 MFMA, K=64) ----
    mlp12_kernel<<<NB, 256, 0, stream>>>(x, w1, b1, w2, b2, H2f, N);
    {   dim3 grid(1, MB);
        gemm_f16_kernel<128, 128, 4, 2, 2, 4, 4, 0><<<grid, 256, 0, stream>>>(
            H2f, Bt0f, b3, S128f, N, 64, 128);
    }

    // ---- GCN1: XCD-sliced agg@128 -> f16 MFMA 128->256 swiz2 ----
    agg_slice_kernel<128><<<2048, 256, 0, stream>>>(
        S128f, offsets, edges, dinv, A128f, qheads, N);
    gemm_f16_kernel<128, 128, 4, 2, 2, 4, 4, 2><<<2 * MB8, 256, 0, stream>>>(
        A128f, Bt1f, g1b, G1f, N, 128, 256);

    // ---- GCN2: XCD-sliced agg@256 -> f16 MFMA 256->512 swiz4 ----
    agg_slice_kernel<256><<<2048, 256, 0, stream>>>(
        G1f, offsets, edges, dinv, A256f, qheads + 8, N);
    gemm_f16_kernel<128, 128, 4, 2, 2, 4, 4, 4><<<4 * MB8, 256, 0, stream>>>(
        A256f, Bt2f, g2b, A512f, N, 256, 512);

    // ---- GCN3: emulated MFMA 512->64 BM=64 (fp16 out) -> agg + softmax ----
    {   dim3 grid(1, MB64);
        gemm_emul_kernel<64, 64, 4, 4, 1, 1, 4><<<grid, 256, 0, stream>>>(
            A512f, Bt3, zbuf, N, 512, 64);
    }
    agg50_softmax_kernel<<<(N + 3) / 4, 256, 0, stream>>>(
        zbuf, offsets, edges, dinv, g3b, out, N);
}

// Round 15
// 442.784 us; speedup vs baseline: 2.0816x; 2.0816x over previous
//
#include <hip/hip_runtime.h>
#include <hip/hip_bf16.h>
#include <math.h>

// ---------------------------------------------------------------------------
// GCN part-seg pipeline.
// R15: revert R14's XCD-sliced agg (922us regression -- 3rd failed gather
//      attack; ~3.2TB/s random-gather is the structural floor). Back to the
//      proven R13 pipeline + int2-packed edges (one 8B load per edge).
// ---------------------------------------------------------------------------

typedef __attribute__((ext_vector_type(8))) short short8;     // 8 bf16
typedef __attribute__((ext_vector_type(8))) _Float16 half8;   // 8 fp16
typedef __attribute__((ext_vector_type(4))) float floatx4;    // 4 fp32

__device__ __forceinline__ unsigned short bf16h(float f) {
    unsigned int u = __float_as_uint(f);
    u += 0x7fff + ((u >> 16) & 1);          // round-to-nearest-even
    return (unsigned short)(u >> 16);
}
__device__ __forceinline__ float bf16f(unsigned short h) {
    return __uint_as_float(((unsigned int)h) << 16);
}

__device__ __forceinline__ void gld_lds16(unsigned short* lds, const unsigned short* g) {
    __builtin_amdgcn_global_load_lds(
        (const __attribute__((address_space(1))) unsigned int*)g,
        (__attribute__((address_space(3))) unsigned int*)lds, 16, 0, 0);
}

// ---------------- degree / CSR build ----------------

__global__ void hist_kernel(const int* __restrict__ dst, int* __restrict__ counts, int e) {
    int g = blockIdx.x * blockDim.x + threadIdx.x;
    if (g < e) atomicAdd(&counts[dst[g]], 1);
}

__global__ void scan1_kernel(const int* __restrict__ counts, int* __restrict__ bsum, int n) {
    __shared__ int buf[256];
    int i = blockIdx.x * 256 + threadIdx.x;
    buf[threadIdx.x] = (i < n) ? counts[i] : 0;
    __syncthreads();
    for (int off = 128; off > 0; off >>= 1) {
        if (threadIdx.x < off) buf[threadIdx.x] += buf[threadIdx.x + off];
        __syncthreads();
    }
    if (threadIdx.x == 0) bsum[blockIdx.x] = buf[0];
}

__global__ void scan2_kernel(const int* __restrict__ bsum, int* __restrict__ bsumx,
                             int* __restrict__ offsets, int nb, int n) {
    __shared__ int buf[256];
    int tid = threadIdx.x;
    int v = (tid < nb) ? bsum[tid] : 0;
    buf[tid] = v;
    __syncthreads();
    for (int off = 1; off < 256; off <<= 1) {
        int t = (tid >= off) ? buf[tid - off] : 0;
        __syncthreads();
        buf[tid] += t;
        __syncthreads();
    }
    if (tid < nb) bsumx[tid] = buf[tid] - v;       // exclusive
    if (tid == 255) offsets[n] = buf[255];          // total
}

__global__ void scan3_kernel(const int* __restrict__ counts, const int* __restrict__ bsumx,
                             int* __restrict__ offsets, int* __restrict__ cursor,
                             float* __restrict__ dinv, int n) {
    __shared__ int buf[256];
    int tid = threadIdx.x;
    int i = blockIdx.x * 256 + tid;
    int c = (i < n) ? counts[i] : 0;
    buf[tid] = c;
    __syncthreads();
    for (int off = 1; off < 256; off <<= 1) {
        int t = (tid >= off) ? buf[tid - off] : 0;
        __syncthreads();
        buf[tid] += t;
        __syncthreads();
    }
    if (i < n) {
        int excl = bsumx[blockIdx.x] + buf[tid] - c;
        offsets[i] = excl;
        cursor[i] = excl;
        dinv[i] = rsqrtf((float)c + 1.0f);
    }
}

__global__ void fill_kernel(const int* __restrict__ src, const int* __restrict__ dst,
                            const float* __restrict__ dinv, int* __restrict__ cursor,
                            int2* __restrict__ edges, int e) {
    int g = blockIdx.x * blockDim.x + threadIdx.x;
    if (g >= e) return;
    int s = src[g], d = dst[g];
    int pos = atomicAdd(&cursor[d], 1);
    edges[pos] = make_int2(s, __float_as_int(dinv[s] * dinv[d]));
}

// ---------------- fused weight prep ----------------
// f16 GEMMs: W[K][N] fp32 -> Btf[N][K] fp16 (transposed).
// GCN3 (emulated): g3w padded -> Bt3[N][2K] bf16 = [Bh;Bl].

__global__ void prepw_kernel(const float* __restrict__ g1w, const float* __restrict__ g2w,
                             const float* __restrict__ g3w, const float* __restrict__ w3,
                             _Float16* __restrict__ Bt1f,
                             _Float16* __restrict__ Bt2f,
                             unsigned short* __restrict__ Bt3,
                             _Float16* __restrict__ Bt0f) {
    int gid = blockIdx.x * blockDim.x + threadIdx.x;
    if (gid < 32768) {                       // g1: K=128, N=256
        int k = gid >> 8, n = gid & 255;
        Bt1f[(size_t)n * 128 + k] = (_Float16)g1w[gid];
    } else if (gid < 32768 + 131072) {       // g2: K=256, N=512
        int idx = gid - 32768;
        int k = idx >> 9, n = idx & 511;
        Bt2f[(size_t)n * 256 + k] = (_Float16)g2w[idx];
    } else if (gid < 32768 + 131072 + 32768) { // g3 padded: K=512, N=64 (bf16 hi/lo)
        int idx = gid - 32768 - 131072;
        int k = idx >> 6, c = idx & 63;
        float w = (c < 50) ? g3w[k * 50 + c] : 0.0f;
        unsigned short h = bf16h(w);
        unsigned short l = bf16h(w - bf16f(h));
        size_t base = (size_t)c * 1024;
        Bt3[base + k]       = h;
        Bt3[base + 512 + k] = l;
    } else if (gid < 32768 + 131072 + 32768 + 8192) { // w3: K=64, N=128
        int idx = gid - 32768 - 131072 - 32768;
        int k = idx >> 7, n = idx & 127;
        Bt0f[(size_t)n * 64 + k] = (_Float16)w3[idx];
    }
}

// ---------------- fused MLP layers 1+2: x[N,3] -> h2 fp16 [N,64] ------------

__global__ __launch_bounds__(256) void mlp12_kernel(
        const float* __restrict__ x,
        const float* __restrict__ w1, const float* __restrict__ b1,
        const float* __restrict__ w2, const float* __restrict__ b2,
        _Float16* __restrict__ H2f, int n) {
    __shared__ float sw1[96], sb1[32], sw2[2048], sb2[64];
    int tid = threadIdx.x;
    if (tid < 96) sw1[tid] = w1[tid];
    if (tid < 32) sb1[tid] = b1[tid];
    if (tid < 64) sb2[tid] = b2[tid];
    for (int i = tid; i < 2048; i += 256) sw2[i] = w2[i];
    __syncthreads();

    int node = blockIdx.x * 256 + tid;
    if (node >= n) return;
    float x0 = x[node * 3 + 0], x1 = x[node * 3 + 1], x2 = x[node * 3 + 2];
    float h1[32];
#pragma unroll
    for (int j = 0; j < 32; j++)
        h1[j] = fmaxf(sb1[j] + x0 * sw1[j] + x1 * sw1[32 + j] + x2 * sw1[64 + j], 0.0f);

    float acc[64];
#pragma unroll
    for (int j = 0; j < 64; j++) acc[j] = sb2[j];
    for (int k = 0; k < 32; k++) {
        float hk = h1[k];
#pragma unroll
        for (int j4 = 0; j4 < 16; j4++) {
            float4 w = *(const float4*)&sw2[k * 64 + j4 * 4];
            acc[j4 * 4 + 0] = fmaf(hk, w.x, acc[j4 * 4 + 0]);
            acc[j4 * 4 + 1] = fmaf(hk, w.y, acc[j4 * 4 + 1]);
            acc[j4 * 4 + 2] = fmaf(hk, w.z, acc[j4 * 4 + 2]);
            acc[j4 * 4 + 3] = fmaf(hk, w.w, acc[j4 * 4 + 3]);
        }
    }
#pragma unroll
    for (int j8 = 0; j8 < 8; j8++) {
        half8 o;
#pragma unroll
        for (int t = 0; t < 8; t++)
            o[t] = (_Float16)fmaxf(acc[j8 * 8 + t], 0.0f);
        *reinterpret_cast<half8*>(&H2f[(size_t)node * 64 + j8 * 8]) = o;
    }
}

// ---------------- native f16 MFMA GEMM --------------------------------------
// C[M,N] = A[M,K](fp16) @ B[K,N](fp16 as Btf[N][K]); fp32 accumulate.
// out = fp16(relu(C+bias)). SWIZCOLS>0: col blocks of a row-block share b%8.

template<int BM, int BN, int WAVES, int WGR, int WGC, int WRF, int WCF, int SWIZCOLS>
__global__ __launch_bounds__(WAVES * 64) void gemm_f16_kernel(
        const _Float16* __restrict__ A, const _Float16* __restrict__ Btf,
        const float* __restrict__ bias, _Float16* __restrict__ C,
        int M, int K, int N) {
    static_assert(WGR * WRF * 16 == BM, "row cover");
    static_assert(WGC * WCF * 16 == BN, "col cover");
    static_assert(WGR * WGC == WAVES, "wave grid");
    constexpr int AUNITS = BM / 16, BUNITS = BN / 16;
    static_assert(AUNITS % WAVES == 0 && BUNITS % WAVES == 0, "staging split");
    __shared__ __align__(16) unsigned short Ash[BM * 32];
    __shared__ __align__(16) unsigned short Bsh[BN * 32];

    int bm, bn;
    if (SWIZCOLS > 0) {
        constexpr int CSH = (SWIZCOLS == 4) ? 2 : 1;
        int b = blockIdx.x;
        int col = (b >> 3) & (SWIZCOLS - 1);
        int row = ((b >> (3 + CSH)) << 3) | (b & 7);
        bm = row * BM;
        bn = col * BN;
        if (bm >= M) return;             // padded row block (uniform exit)
    } else {
        bm = blockIdx.y * BM;
        bn = blockIdx.x * BN;
    }

    const int tid  = threadIdx.x;
    const int lane = tid & 63;
    const int wave = tid >> 6;
    const int wr0 = (wave / WGC) * (WRF * 16);
    const int wc0 = (wave % WGC) * (WCF * 16);
    const int lr   = lane & 15;
    const int quad = lane >> 4;
    const int arow = lane >> 2;          // row within 16-row group
    const int acol = (lane & 3) * 8;     // halves within 32-half row

    floatx4 acc[WRF][WCF];
#pragma unroll
    for (int i = 0; i < WRF; i++)
#pragma unroll
        for (int j = 0; j < WCF; j++) acc[i][j] = floatx4{0.f, 0.f, 0.f, 0.f};

    for (int k0 = 0; k0 < K; k0 += 32) {
#pragma unroll
        for (int u = 0; u < AUNITS / WAVES; u++) {
            int grp = wave + u * WAVES;
            int gm = bm + grp * 16 + arow;
            if (gm >= M) gm = M - 1;     // clamp: garbage rows discarded at store
            gld_lds16(&Ash[grp * 512],
                      (const unsigned short*)(A + (size_t)gm * K + k0 + acol));
        }
#pragma unroll
        for (int u = 0; u < BUNITS / WAVES; u++) {
            int grp = wave + u * WAVES;
            int gr = bn + grp * 16 + arow;
            gld_lds16(&Bsh[grp * 512],
                      (const unsigned short*)(Btf + (size_t)gr * K + k0 + acol));
        }
        __syncthreads();

        half8 af[WRF], bf[WCF];
#pragma unroll
        for (int i = 0; i < WRF; i++)
            af[i] = *reinterpret_cast<const half8*>(
                &Ash[(wr0 + i * 16 + lr) * 32 + quad * 8]);
#pragma unroll
        for (int j = 0; j < WCF; j++)
            bf[j] = *reinterpret_cast<const half8*>(
                &Bsh[(wc0 + j * 16 + lr) * 32 + quad * 8]);
#pragma unroll
        for (int i = 0; i < WRF; i++)
#pragma unroll
            for (int j = 0; j < WCF; j++)
                acc[i][j] = __builtin_amdgcn_mfma_f32_16x16x32_f16(
                    af[i], bf[j], acc[i][j], 0, 0, 0);
        __syncthreads();
    }

    // epilogue: C/D layout col=lane&15, row=quad*4+reg (m89-verified)
#pragma unroll
    for (int i = 0; i < WRF; i++) {
#pragma unroll
        for (int j = 0; j < WCF; j++) {
            int gc = bn + wc0 + j * 16 + lr;
#pragma unroll
            for (int reg = 0; reg < 4; reg++) {
                int gr = bm + wr0 + i * 16 + quad * 4 + reg;
                if (gr >= M) continue;
                float v = fmaxf(acc[i][j][reg] + bias[gc], 0.0f);
                C[(size_t)gr * N + gc] = (_Float16)v;
            }
        }
    }
}

// ---------------- emulated GEMM for GCN3 (logit layer) ----------------------
// A fp16 plane (in-register bf16 hi/lo split), B = Bt[N][2K] bf16 [Bh;Bl].
// out = fp16(C) raw (no bias/relu).

template<int BM, int BN, int WAVES, int WGR, int WGC, int WRF, int WCF>
__global__ __launch_bounds__(WAVES * 64) void gemm_emul_kernel(
        const _Float16* __restrict__ Af, const unsigned short* __restrict__ Bt,
        _Float16* __restrict__ C, int M, int K, int N) {
    static_assert(WGR * WRF * 16 == BM, "row cover");
    static_assert(WGC * WCF * 16 == BN, "col cover");
    static_assert(WGR * WGC == WAVES, "wave grid");
    constexpr int AUNITS = BM / 16, BUNITS = BN / 8;
    static_assert(AUNITS % WAVES == 0 && BUNITS % WAVES == 0, "staging split");
    __shared__ __align__(16) unsigned short Ash[BM * 32];
    __shared__ __align__(16) unsigned short Bsh[BN * 32];
    __shared__ __align__(16) unsigned short Bsl[BN * 32];

    const int bm = blockIdx.y * BM;
    const int bn = blockIdx.x * BN;
    const int tid  = threadIdx.x;
    const int lane = tid & 63;
    const int wave = tid >> 6;
    const int K2 = 2 * K;
    const int wr0 = (wave / WGC) * (WRF * 16);
    const int wc0 = (wave % WGC) * (WCF * 16);
    const int lr   = lane & 15;
    const int quad = lane >> 4;
    const int arow = lane >> 2;
    const int acol = (lane & 3) * 8;

    floatx4 acc[WRF][WCF];
#pragma unroll
    for (int i = 0; i < WRF; i++)
#pragma unroll
        for (int j = 0; j < WCF; j++) acc[i][j] = floatx4{0.f, 0.f, 0.f, 0.f};

    for (int k0 = 0; k0 < K; k0 += 32) {
#pragma unroll
        for (int u = 0; u < AUNITS / WAVES; u++) {
            int grp = wave + u * WAVES;
            int gm = bm + grp * 16 + arow;
            if (gm >= M) gm = M - 1;
            gld_lds16(&Ash[grp * 512],
                      (const unsigned short*)(Af + (size_t)gm * K + k0 + acol));
        }
#pragma unroll
        for (int u = 0; u < BUNITS / WAVES; u++) {
            int unit = wave + u * WAVES;
            int grp = unit >> 1, pl = unit & 1;
            int gr = bn + grp * 16 + arow;
            size_t go = (size_t)gr * K2 + k0 + acol + (pl ? K : 0);
            if (pl) gld_lds16(&Bsl[grp * 512], Bt + go);
            else    gld_lds16(&Bsh[grp * 512], Bt + go);
        }
        __syncthreads();

        short8 ahf[WRF], alf[WRF], bhf[WCF], blf[WCF];
#pragma unroll
        for (int i = 0; i < WRF; i++) {
            half8 av = *reinterpret_cast<const half8*>(
                &Ash[(wr0 + i * 16 + lr) * 32 + quad * 8]);
#pragma unroll
            for (int t = 0; t < 8; t++) {
                float f = (float)av[t];
                unsigned short h = bf16h(f);
                ahf[i][t] = (short)h;
                alf[i][t] = (short)bf16h(f - bf16f(h));
            }
        }
#pragma unroll
        for (int j = 0; j < WCF; j++) {
            int ro = (wc0 + j * 16 + lr) * 32 + quad * 8;
            bhf[j] = *reinterpret_cast<const short8*>(&Bsh[ro]);
            blf[j] = *reinterpret_cast<const short8*>(&Bsl[ro]);
        }
#pragma unroll
        for (int i = 0; i < WRF; i++)
#pragma unroll
            for (int j = 0; j < WCF; j++) {
                acc[i][j] = __builtin_amdgcn_mfma_f32_16x16x32_bf16(
                    ahf[i], bhf[j], acc[i][j], 0, 0, 0);
                acc[i][j] = __builtin_amdgcn_mfma_f32_16x16x32_bf16(
                    ahf[i], blf[j], acc[i][j], 0, 0, 0);
                acc[i][j] = __builtin_amdgcn_mfma_f32_16x16x32_bf16(
                    alf[i], bhf[j], acc[i][j], 0, 0, 0);
            }
        __syncthreads();
    }

#pragma unroll
    for (int i = 0; i < WRF; i++) {
#pragma unroll
        for (int j = 0; j < WCF; j++) {
            int gc = bn + wc0 + j * 16 + lr;
#pragma unroll
            for (int reg = 0; reg < 4; reg++) {
                int gr = bm + wr0 + i * 16 + quad * 4 + reg;
                if (gr >= M) continue;
                C[(size_t)gr * N + gc] = (_Float16)acc[i][j][reg];
            }
        }
    }
}

// ---------------- aggregation from fp16 table -> fp16 plane -----------------
// thread per (node, half8); int2-packed edges (one 8B load per edge).

template<int F>
__global__ void agg_f16_kernel(const _Float16* __restrict__ table,
                               const int* __restrict__ offsets,
                               const int2* __restrict__ edges,
                               const float* __restrict__ dinv,
                               _Float16* __restrict__ Aout, int n) {
    constexpr int F8 = F / 8;
    int gid = blockIdx.x * blockDim.x + threadIdx.x;
    if (gid >= n * F8) return;
    int node = gid / F8;                 // F8 pow2 -> shift
    int c8 = (gid - node * F8) * 8;

    float acc[8];
#pragma unroll
    for (int i = 0; i < 8; i++) acc[i] = 0.0f;

    int beg = offsets[node], end = offsets[node + 1];
    for (int e = beg; e < end; ++e) {
        int2 E = edges[e];
        float w = __int_as_float(E.y);
        half8 r = *reinterpret_cast<const half8*>(table + (size_t)E.x * F + c8);
#pragma unroll
        for (int i = 0; i < 8; i++) acc[i] = fmaf((float)r[i], w, acc[i]);
    }
    float dv = dinv[node];
    float sw = dv * dv;
    half8 r = *reinterpret_cast<const half8*>(table + (size_t)node * F + c8);
#pragma unroll
    for (int i = 0; i < 8; i++) acc[i] = fmaf((float)r[i], sw, acc[i]);

    half8 o;
#pragma unroll
    for (int i = 0; i < 8; i++) o[i] = (_Float16)acc[i];
    *reinterpret_cast<half8*>(&Aout[(size_t)node * F + c8]) = o;
}

// ---------------- fused final aggregation + softmax: one wave per node ------
// z[N,64] fp16 (cols 50..63 zero); out[N,50] = softmax(AGG(z)+bias).
// Edge loop unrolled 4x (L2-latency-bound regime), int2 edges.

__global__ void agg50_softmax_kernel(const _Float16* __restrict__ z,
                                     const int* __restrict__ offsets,
                                     const int2* __restrict__ edges,
                                     const float* __restrict__ dinv,
                                     const float* __restrict__ bias,
                                     float* __restrict__ out, int n) {
    int node = blockIdx.x * 4 + (threadIdx.x >> 6);
    int lane = threadIdx.x & 63;
    if (node >= n) return;

    float a0 = 0.f, a1 = 0.f, a2 = 0.f, a3 = 0.f;
    int beg = offsets[node], end = offsets[node + 1];
    int e = beg;
    for (; e + 4 <= end; e += 4) {
        int2 E0 = edges[e + 0], E1 = edges[e + 1];
        int2 E2 = edges[e + 2], E3 = edges[e + 3];
        float r0 = (float)z[(size_t)E0.x * 64 + lane];
        float r1 = (float)z[(size_t)E1.x * 64 + lane];
        float r2 = (float)z[(size_t)E2.x * 64 + lane];
        float r3 = (float)z[(size_t)E3.x * 64 + lane];
        a0 = fmaf(r0, __int_as_float(E0.y), a0);
        a1 = fmaf(r1, __int_as_float(E1.y), a1);
        a2 = fmaf(r2, __int_as_float(E2.y), a2);
        a3 = fmaf(r3, __int_as_float(E3.y), a3);
    }
    for (; e < end; ++e) {
        int2 E0 = edges[e];
        a0 = fmaf((float)z[(size_t)E0.x * 64 + lane], __int_as_float(E0.y), a0);
    }

    float dv = dinv[node];
    float a = fmaf((float)z[(size_t)node * 64 + lane], dv * dv,
                   (a0 + a1) + (a2 + a3));

    float v = (lane < 50) ? a + bias[lane] : -INFINITY;
    float m = v;
#pragma unroll
    for (int off = 32; off > 0; off >>= 1) m = fmaxf(m, __shfl_xor(m, off));
    float ex = (lane < 50) ? expf(v - m) : 0.0f;
    float s = ex;
#pragma unroll
    for (int off = 32; off > 0; off >>= 1) s += __shfl_xor(s, off);
    if (lane < 50) out[(size_t)node * 50 + lane] = ex / s;
}

// ---------------------------------------------------------------------------

extern "C" void kernel_launch(void* const* d_in, const int* in_sizes, int n_in,
                              void* d_out, int out_size, void* d_ws, size_t ws_size,
                              hipStream_t stream) {
    const float* x    = (const float*)d_in[0];
    const int*   ei   = (const int*)  d_in[1];
    const float* w1   = (const float*)d_in[2];
    const float* b1   = (const float*)d_in[3];
    const float* w2   = (const float*)d_in[4];
    const float* b2   = (const float*)d_in[5];
    const float* w3   = (const float*)d_in[6];
    const float* b3   = (const float*)d_in[7];
    const float* g1w  = (const float*)d_in[8];
    const float* g1b  = (const float*)d_in[9];
    const float* g2w  = (const float*)d_in[10];
    const float* g2b  = (const float*)d_in[11];
    const float* g3w  = (const float*)d_in[12];
    const float* g3b  = (const float*)d_in[13];
    float* out = (float*)d_out;

    const int N = in_sizes[0] / 3;      // 50000
    const int E = in_sizes[1] / 2;      // 800000
    const int* src = ei;
    const int* dst = ei + E;
    const int NB = (N + 255) / 256;     // 196

    // ---- workspace arena with liveness-based region reuse ----
    char* ws = (char*)d_ws;
    size_t off = 0;
    auto alloc = [&](size_t bytes) -> char* {
        char* p = ws + off;
        off = (off + bytes + 255) & ~(size_t)255;
        return p;
    };
    int*   counts  = (int*)  alloc((size_t)N * 4);
    int*   offsets = (int*)  alloc((size_t)(N + 1) * 4);
    int*   cursor  = (int*)  alloc((size_t)N * 4);
    float* dinv    = (float*)alloc((size_t)N * 4);
    int*   bsum    = (int*)  alloc((size_t)256 * 4);
    int*   bsumx   = (int*)  alloc((size_t)256 * 4);
    int2*  edges   = (int2*) alloc((size_t)E * 8);
    _Float16* Bt1f = (_Float16*)alloc((size_t)256 * 128 * 2);
    _Float16* Bt2f = (_Float16*)alloc((size_t)512 * 256 * 2);
    unsigned short* Bt3 = (unsigned short*)alloc((size_t)64 * 1024 * 2);
    _Float16* Bt0f = (_Float16*)alloc((size_t)128 * 64 * 2);
    char* R1 = alloc((size_t)N * 256 * 4);   // 51.2 MB
    char* R2 = alloc((size_t)N * 256 * 4);   // 51.2 MB
    char* R3 = alloc((size_t)N * 512 * 2);   // 51.2 MB (A512 fp16)
    (void)ws_size;

    // R1 phase 1: S128f [N,128] fp16 | A128f [N,128] fp16   phase 2: A256f
    _Float16*       S128f = (_Float16*)R1;
    _Float16*       A128f = (_Float16*)(R1 + (size_t)N * 128 * 2);
    _Float16*       A256f = (_Float16*)R1;
    // R2 phase 1: H2f [N,64] fp16   phase 2: G1f [N,256] fp16   phase 3: zbuf
    _Float16*       H2f  = (_Float16*)R2;
    _Float16*       G1f  = (_Float16*)R2;
    _Float16*       zbuf = (_Float16*)R2;
    // R3: A512f fp16 [N,512]
    _Float16*       A512f = (_Float16*)R3;

    // ---- degree + CSR + weight prep ----
    hipMemsetAsync(counts, 0, (size_t)N * 4, stream);
    hist_kernel<<<(E + 255) / 256, 256, 0, stream>>>(dst, counts, E);
    scan1_kernel<<<NB, 256, 0, stream>>>(counts, bsum, N);
    scan2_kernel<<<1, 256, 0, stream>>>(bsum, bsumx, offsets, NB, N);
    scan3_kernel<<<NB, 256, 0, stream>>>(counts, bsumx, offsets, cursor, dinv, N);
    fill_kernel<<<(E + 255) / 256, 256, 0, stream>>>(src, dst, dinv, cursor, edges, E);
    prepw_kernel<<<(204800 + 255) / 256, 256, 0, stream>>>(
        g1w, g2w, g3w, w3, Bt1f, Bt2f, Bt3, Bt0f);

    const int MB = (N + 127) / 128;     // 391 row-blocks (BM=128)
    const int MB8 = (MB + 7) & ~7;      // 392 (pad to 8 for swizzle)
    const int MB64 = (N + 63) / 64;     // 782 row-blocks (BM=64)

    // ---- MLP: x -> h2 fp16 (fused), h2 -> h3 fp16 (f16 MFMA, K=64) ----
    mlp12_kernel<<<NB, 256, 0, stream>>>(x, w1, b1, w2, b2, H2f, N);
    {   dim3 grid(1, MB);
        gemm_f16_kernel<128, 128, 4, 2, 2, 4, 4, 0><<<grid, 256, 0, stream>>>(
            H2f, Bt0f, b3, S128f, N, 64, 128);
    }

    // ---- GCN1: agg@128 -> f16 MFMA 128->256 swiz2 ----
    agg_f16_kernel<128><<<((size_t)N * 16 + 255) / 256, 256, 0, stream>>>(
        S128f, offsets, edges, dinv, A128f, N);
    gemm_f16_kernel<128, 128, 4, 2, 2, 4, 4, 2><<<2 * MB8, 256, 0, stream>>>(
        A128f, Bt1f, g1b, G1f, N, 128, 256);

    // ---- GCN2: agg@256 -> f16 MFMA 256->512 swiz4 ----
    agg_f16_kernel<256><<<((size_t)N * 32 + 255) / 256, 256, 0, stream>>>(
        G1f, offsets, edges, dinv, A256f, N);
    gemm_f16_kernel<128, 128, 4, 2, 2, 4, 4, 4><<<4 * MB8, 256, 0, stream>>>(
        A256f, Bt2f, g2b, A512f, N, 256, 512);

    // ---- GCN3: emulated MFMA 512->64 BM=64 (fp16 out) -> agg + softmax ----
    {   dim3 grid(1, MB64);
        gemm_emul_kernel<64, 64, 4, 4, 1, 1, 4><<<grid, 256, 0, stream>>>(
            A512f, Bt3, zbuf, N, 512, 64);
    }
    agg50_softmax_kernel<<<(N + 3) / 4, 256, 0, stream>>>(
        zbuf, offsets, edges, dinv, g3b, out, N);
}

// Round 16
// 439.528 us; speedup vs baseline: 2.0970x; 1.0074x over previous
//
#include <hip/hip_runtime.h>
#include <hip/hip_bf16.h>
#include <math.h>

// ---------------------------------------------------------------------------
// GCN part-seg pipeline.
// R16: GCN3 GEMM -> native f16 weights (emulation deleted; fp16-weight safety
//      proven on the other 3 GEMMs + z already fp16 since R9). agg50_softmax
//      unrolled 8x (L2-latency-bound). Rest identical to R15.
// ---------------------------------------------------------------------------

typedef __attribute__((ext_vector_type(8))) _Float16 half8;   // 8 fp16
typedef __attribute__((ext_vector_type(4))) float floatx4;    // 4 fp32

__device__ __forceinline__ void gld_lds16(unsigned short* lds, const unsigned short* g) {
    __builtin_amdgcn_global_load_lds(
        (const __attribute__((address_space(1))) unsigned int*)g,
        (__attribute__((address_space(3))) unsigned int*)lds, 16, 0, 0);
}

// ---------------- degree / CSR build ----------------

__global__ void hist_kernel(const int* __restrict__ dst, int* __restrict__ counts, int e) {
    int g = blockIdx.x * blockDim.x + threadIdx.x;
    if (g < e) atomicAdd(&counts[dst[g]], 1);
}

__global__ void scan1_kernel(const int* __restrict__ counts, int* __restrict__ bsum, int n) {
    __shared__ int buf[256];
    int i = blockIdx.x * 256 + threadIdx.x;
    buf[threadIdx.x] = (i < n) ? counts[i] : 0;
    __syncthreads();
    for (int off = 128; off > 0; off >>= 1) {
        if (threadIdx.x < off) buf[threadIdx.x] += buf[threadIdx.x + off];
        __syncthreads();
    }
    if (threadIdx.x == 0) bsum[blockIdx.x] = buf[0];
}

__global__ void scan2_kernel(const int* __restrict__ bsum, int* __restrict__ bsumx,
                             int* __restrict__ offsets, int nb, int n) {
    __shared__ int buf[256];
    int tid = threadIdx.x;
    int v = (tid < nb) ? bsum[tid] : 0;
    buf[tid] = v;
    __syncthreads();
    for (int off = 1; off < 256; off <<= 1) {
        int t = (tid >= off) ? buf[tid - off] : 0;
        __syncthreads();
        buf[tid] += t;
        __syncthreads();
    }
    if (tid < nb) bsumx[tid] = buf[tid] - v;       // exclusive
    if (tid == 255) offsets[n] = buf[255];          // total
}

__global__ void scan3_kernel(const int* __restrict__ counts, const int* __restrict__ bsumx,
                             int* __restrict__ offsets, int* __restrict__ cursor,
                             float* __restrict__ dinv, int n) {
    __shared__ int buf[256];
    int tid = threadIdx.x;
    int i = blockIdx.x * 256 + tid;
    int c = (i < n) ? counts[i] : 0;
    buf[tid] = c;
    __syncthreads();
    for (int off = 1; off < 256; off <<= 1) {
        int t = (tid >= off) ? buf[tid - off] : 0;
        __syncthreads();
        buf[tid] += t;
        __syncthreads();
    }
    if (i < n) {
        int excl = bsumx[blockIdx.x] + buf[tid] - c;
        offsets[i] = excl;
        cursor[i] = excl;
        dinv[i] = rsqrtf((float)c + 1.0f);
    }
}

__global__ void fill_kernel(const int* __restrict__ src, const int* __restrict__ dst,
                            const float* __restrict__ dinv, int* __restrict__ cursor,
                            int2* __restrict__ edges, int e) {
    int g = blockIdx.x * blockDim.x + threadIdx.x;
    if (g >= e) return;
    int s = src[g], d = dst[g];
    int pos = atomicAdd(&cursor[d], 1);
    edges[pos] = make_int2(s, __float_as_int(dinv[s] * dinv[d]));
}

// ---------------- fused weight prep: W[K][N] fp32 -> Btf[N][K] fp16 ---------
// g3w padded 50->64 cols.

__global__ void prepw_kernel(const float* __restrict__ g1w, const float* __restrict__ g2w,
                             const float* __restrict__ g3w, const float* __restrict__ w3,
                             _Float16* __restrict__ Bt1f,
                             _Float16* __restrict__ Bt2f,
                             _Float16* __restrict__ Bt3f,
                             _Float16* __restrict__ Bt0f) {
    int gid = blockIdx.x * blockDim.x + threadIdx.x;
    if (gid < 32768) {                       // g1: K=128, N=256
        int k = gid >> 8, n = gid & 255;
        Bt1f[(size_t)n * 128 + k] = (_Float16)g1w[gid];
    } else if (gid < 32768 + 131072) {       // g2: K=256, N=512
        int idx = gid - 32768;
        int k = idx >> 9, n = idx & 511;
        Bt2f[(size_t)n * 256 + k] = (_Float16)g2w[idx];
    } else if (gid < 32768 + 131072 + 32768) { // g3 padded: K=512, N=64
        int idx = gid - 32768 - 131072;
        int k = idx >> 6, c = idx & 63;
        float w = (c < 50) ? g3w[k * 50 + c] : 0.0f;
        Bt3f[(size_t)c * 512 + k] = (_Float16)w;
    } else if (gid < 32768 + 131072 + 32768 + 8192) { // w3: K=64, N=128
        int idx = gid - 32768 - 131072 - 32768;
        int k = idx >> 7, n = idx & 127;
        Bt0f[(size_t)n * 64 + k] = (_Float16)w3[idx];
    }
}

// ---------------- fused MLP layers 1+2: x[N,3] -> h2 fp16 [N,64] ------------

__global__ __launch_bounds__(256) void mlp12_kernel(
        const float* __restrict__ x,
        const float* __restrict__ w1, const float* __restrict__ b1,
        const float* __restrict__ w2, const float* __restrict__ b2,
        _Float16* __restrict__ H2f, int n) {
    __shared__ float sw1[96], sb1[32], sw2[2048], sb2[64];
    int tid = threadIdx.x;
    if (tid < 96) sw1[tid] = w1[tid];
    if (tid < 32) sb1[tid] = b1[tid];
    if (tid < 64) sb2[tid] = b2[tid];
    for (int i = tid; i < 2048; i += 256) sw2[i] = w2[i];
    __syncthreads();

    int node = blockIdx.x * 256 + tid;
    if (node >= n) return;
    float x0 = x[node * 3 + 0], x1 = x[node * 3 + 1], x2 = x[node * 3 + 2];
    float h1[32];
#pragma unroll
    for (int j = 0; j < 32; j++)
        h1[j] = fmaxf(sb1[j] + x0 * sw1[j] + x1 * sw1[32 + j] + x2 * sw1[64 + j], 0.0f);

    float acc[64];
#pragma unroll
    for (int j = 0; j < 64; j++) acc[j] = sb2[j];
    for (int k = 0; k < 32; k++) {
        float hk = h1[k];
#pragma unroll
        for (int j4 = 0; j4 < 16; j4++) {
            float4 w = *(const float4*)&sw2[k * 64 + j4 * 4];
            acc[j4 * 4 + 0] = fmaf(hk, w.x, acc[j4 * 4 + 0]);
            acc[j4 * 4 + 1] = fmaf(hk, w.y, acc[j4 * 4 + 1]);
            acc[j4 * 4 + 2] = fmaf(hk, w.z, acc[j4 * 4 + 2]);
            acc[j4 * 4 + 3] = fmaf(hk, w.w, acc[j4 * 4 + 3]);
        }
    }
#pragma unroll
    for (int j8 = 0; j8 < 8; j8++) {
        half8 o;
#pragma unroll
        for (int t = 0; t < 8; t++)
            o[t] = (_Float16)fmaxf(acc[j8 * 8 + t], 0.0f);
        *reinterpret_cast<half8*>(&H2f[(size_t)node * 64 + j8 * 8]) = o;
    }
}

// ---------------- native f16 MFMA GEMM --------------------------------------
// C[M,N] = A[M,K](fp16) @ B[K,N](fp16 as Btf[N][K]); fp32 accumulate.
// RAW=false: out = fp16(relu(C+bias)). RAW=true: out = fp16(C).
// SWIZCOLS>0: col blocks of a row-block share b%8 (XCD L2 cooperation,
// verified R12: FETCH 106->16 MB).

template<int BM, int BN, int WAVES, int WGR, int WGC, int WRF, int WCF,
         int SWIZCOLS, bool RAW>
__global__ __launch_bounds__(WAVES * 64) void gemm_f16_kernel(
        const _Float16* __restrict__ A, const _Float16* __restrict__ Btf,
        const float* __restrict__ bias, _Float16* __restrict__ C,
        int M, int K, int N) {
    static_assert(WGR * WRF * 16 == BM, "row cover");
    static_assert(WGC * WCF * 16 == BN, "col cover");
    static_assert(WGR * WGC == WAVES, "wave grid");
    constexpr int AUNITS = BM / 16, BUNITS = BN / 16;
    static_assert(AUNITS % WAVES == 0 && BUNITS % WAVES == 0, "staging split");
    __shared__ __align__(16) unsigned short Ash[BM * 32];
    __shared__ __align__(16) unsigned short Bsh[BN * 32];

    int bm, bn;
    if (SWIZCOLS > 0) {
        constexpr int CSH = (SWIZCOLS == 4) ? 2 : 1;
        int b = blockIdx.x;
        int col = (b >> 3) & (SWIZCOLS - 1);
        int row = ((b >> (3 + CSH)) << 3) | (b & 7);
        bm = row * BM;
        bn = col * BN;
        if (bm >= M) return;             // padded row block (uniform exit)
    } else {
        bm = blockIdx.y * BM;
        bn = blockIdx.x * BN;
    }

    const int tid  = threadIdx.x;
    const int lane = tid & 63;
    const int wave = tid >> 6;
    const int wr0 = (wave / WGC) * (WRF * 16);
    const int wc0 = (wave % WGC) * (WCF * 16);
    const int lr   = lane & 15;
    const int quad = lane >> 4;
    const int arow = lane >> 2;          // row within 16-row group
    const int acol = (lane & 3) * 8;     // halves within 32-half row

    floatx4 acc[WRF][WCF];
#pragma unroll
    for (int i = 0; i < WRF; i++)
#pragma unroll
        for (int j = 0; j < WCF; j++) acc[i][j] = floatx4{0.f, 0.f, 0.f, 0.f};

    for (int k0 = 0; k0 < K; k0 += 32) {
#pragma unroll
        for (int u = 0; u < AUNITS / WAVES; u++) {
            int grp = wave + u * WAVES;
            int gm = bm + grp * 16 + arow;
            if (gm >= M) gm = M - 1;     // clamp: garbage rows discarded at store
            gld_lds16(&Ash[grp * 512],
                      (const unsigned short*)(A + (size_t)gm * K + k0 + acol));
        }
#pragma unroll
        for (int u = 0; u < BUNITS / WAVES; u++) {
            int grp = wave + u * WAVES;
            int gr = bn + grp * 16 + arow;
            gld_lds16(&Bsh[grp * 512],
                      (const unsigned short*)(Btf + (size_t)gr * K + k0 + acol));
        }
        __syncthreads();

        half8 af[WRF], bf[WCF];
#pragma unroll
        for (int i = 0; i < WRF; i++)
            af[i] = *reinterpret_cast<const half8*>(
                &Ash[(wr0 + i * 16 + lr) * 32 + quad * 8]);
#pragma unroll
        for (int j = 0; j < WCF; j++)
            bf[j] = *reinterpret_cast<const half8*>(
                &Bsh[(wc0 + j * 16 + lr) * 32 + quad * 8]);
#pragma unroll
        for (int i = 0; i < WRF; i++)
#pragma unroll
            for (int j = 0; j < WCF; j++)
                acc[i][j] = __builtin_amdgcn_mfma_f32_16x16x32_f16(
                    af[i], bf[j], acc[i][j], 0, 0, 0);
        __syncthreads();
    }

    // epilogue: C/D layout col=lane&15, row=quad*4+reg (m89-verified)
#pragma unroll
    for (int i = 0; i < WRF; i++) {
#pragma unroll
        for (int j = 0; j < WCF; j++) {
            int gc = bn + wc0 + j * 16 + lr;
#pragma unroll
            for (int reg = 0; reg < 4; reg++) {
                int gr = bm + wr0 + i * 16 + quad * 4 + reg;
                if (gr >= M) continue;
                float v = acc[i][j][reg];
                if (!RAW) v = fmaxf(v + bias[gc], 0.0f);
                C[(size_t)gr * N + gc] = (_Float16)v;
            }
        }
    }
}

// ---------------- aggregation from fp16 table -> fp16 plane -----------------
// thread per (node, half8); int2-packed edges (one 8B load per edge).

template<int F>
__global__ void agg_f16_kernel(const _Float16* __restrict__ table,
                               const int* __restrict__ offsets,
                               const int2* __restrict__ edges,
                               const float* __restrict__ dinv,
                               _Float16* __restrict__ Aout, int n) {
    constexpr int F8 = F / 8;
    int gid = blockIdx.x * blockDim.x + threadIdx.x;
    if (gid >= n * F8) return;
    int node = gid / F8;                 // F8 pow2 -> shift
    int c8 = (gid - node * F8) * 8;

    float acc[8];
#pragma unroll
    for (int i = 0; i < 8; i++) acc[i] = 0.0f;

    int beg = offsets[node], end = offsets[node + 1];
    for (int e = beg; e < end; ++e) {
        int2 E = edges[e];
        float w = __int_as_float(E.y);
        half8 r = *reinterpret_cast<const half8*>(table + (size_t)E.x * F + c8);
#pragma unroll
        for (int i = 0; i < 8; i++) acc[i] = fmaf((float)r[i], w, acc[i]);
    }
    float dv = dinv[node];
    float sw = dv * dv;
    half8 r = *reinterpret_cast<const half8*>(table + (size_t)node * F + c8);
#pragma unroll
    for (int i = 0; i < 8; i++) acc[i] = fmaf((float)r[i], sw, acc[i]);

    half8 o;
#pragma unroll
    for (int i = 0; i < 8; i++) o[i] = (_Float16)acc[i];
    *reinterpret_cast<half8*>(&Aout[(size_t)node * F + c8]) = o;
}

// ---------------- fused final aggregation + softmax: one wave per node ------
// z[N,64] fp16 (cols 50..63 zero); out[N,50] = softmax(AGG(z)+bias).
// Edge loop unrolled 8x, independent accumulators (L2-latency-bound).

__global__ void agg50_softmax_kernel(const _Float16* __restrict__ z,
                                     const int* __restrict__ offsets,
                                     const int2* __restrict__ edges,
                                     const float* __restrict__ dinv,
                                     const float* __restrict__ bias,
                                     float* __restrict__ out, int n) {
    int node = blockIdx.x * 4 + (threadIdx.x >> 6);
    int lane = threadIdx.x & 63;
    if (node >= n) return;

    float a0 = 0.f, a1 = 0.f, a2 = 0.f, a3 = 0.f;
    float a4 = 0.f, a5 = 0.f, a6 = 0.f, a7 = 0.f;
    int beg = offsets[node], end = offsets[node + 1];
    int e = beg;
    for (; e + 8 <= end; e += 8) {
        int2 E0 = edges[e + 0], E1 = edges[e + 1];
        int2 E2 = edges[e + 2], E3 = edges[e + 3];
        int2 E4 = edges[e + 4], E5 = edges[e + 5];
        int2 E6 = edges[e + 6], E7 = edges[e + 7];
        float r0 = (float)z[(size_t)E0.x * 64 + lane];
        float r1 = (float)z[(size_t)E1.x * 64 + lane];
        float r2 = (float)z[(size_t)E2.x * 64 + lane];
        float r3 = (float)z[(size_t)E3.x * 64 + lane];
        float r4 = (float)z[(size_t)E4.x * 64 + lane];
        float r5 = (float)z[(size_t)E5.x * 64 + lane];
        float r6 = (float)z[(size_t)E6.x * 64 + lane];
        float r7 = (float)z[(size_t)E7.x * 64 + lane];
        a0 = fmaf(r0, __int_as_float(E0.y), a0);
        a1 = fmaf(r1, __int_as_float(E1.y), a1);
        a2 = fmaf(r2, __int_as_float(E2.y), a2);
        a3 = fmaf(r3, __int_as_float(E3.y), a3);
        a4 = fmaf(r4, __int_as_float(E4.y), a4);
        a5 = fmaf(r5, __int_as_float(E5.y), a5);
        a6 = fmaf(r6, __int_as_float(E6.y), a6);
        a7 = fmaf(r7, __int_as_float(E7.y), a7);
    }
    for (; e < end; ++e) {
        int2 E0 = edges[e];
        a0 = fmaf((float)z[(size_t)E0.x * 64 + lane], __int_as_float(E0.y), a0);
    }

    float dv = dinv[node];
    float a = fmaf((float)z[(size_t)node * 64 + lane], dv * dv,
                   ((a0 + a1) + (a2 + a3)) + ((a4 + a5) + (a6 + a7)));

    float v = (lane < 50) ? a + bias[lane] : -INFINITY;
    float m = v;
#pragma unroll
    for (int off = 32; off > 0; off >>= 1) m = fmaxf(m, __shfl_xor(m, off));
    float ex = (lane < 50) ? expf(v - m) : 0.0f;
    float s = ex;
#pragma unroll
    for (int off = 32; off > 0; off >>= 1) s += __shfl_xor(s, off);
    if (lane < 50) out[(size_t)node * 50 + lane] = ex / s;
}

// ---------------------------------------------------------------------------

extern "C" void kernel_launch(void* const* d_in, const int* in_sizes, int n_in,
                              void* d_out, int out_size, void* d_ws, size_t ws_size,
                              hipStream_t stream) {
    const float* x    = (const float*)d_in[0];
    const int*   ei   = (const int*)  d_in[1];
    const float* w1   = (const float*)d_in[2];
    const float* b1   = (const float*)d_in[3];
    const float* w2   = (const float*)d_in[4];
    const float* b2   = (const float*)d_in[5];
    const float* w3   = (const float*)d_in[6];
    const float* b3   = (const float*)d_in[7];
    const float* g1w  = (const float*)d_in[8];
    const float* g1b  = (const float*)d_in[9];
    const float* g2w  = (const float*)d_in[10];
    const float* g2b  = (const float*)d_in[11];
    const float* g3w  = (const float*)d_in[12];
    const float* g3b  = (const float*)d_in[13];
    float* out = (float*)d_out;

    const int N = in_sizes[0] / 3;      // 50000
    const int E = in_sizes[1] / 2;      // 800000
    const int* src = ei;
    const int* dst = ei + E;
    const int NB = (N + 255) / 256;     // 196

    // ---- workspace arena with liveness-based region reuse ----
    char* ws = (char*)d_ws;
    size_t off = 0;
    auto alloc = [&](size_t bytes) -> char* {
        char* p = ws + off;
        off = (off + bytes + 255) & ~(size_t)255;
        return p;
    };
    int*   counts  = (int*)  alloc((size_t)N * 4);
    int*   offsets = (int*)  alloc((size_t)(N + 1) * 4);
    int*   cursor  = (int*)  alloc((size_t)N * 4);
    float* dinv    = (float*)alloc((size_t)N * 4);
    int*   bsum    = (int*)  alloc((size_t)256 * 4);
    int*   bsumx   = (int*)  alloc((size_t)256 * 4);
    int2*  edges   = (int2*) alloc((size_t)E * 8);
    _Float16* Bt1f = (_Float16*)alloc((size_t)256 * 128 * 2);
    _Float16* Bt2f = (_Float16*)alloc((size_t)512 * 256 * 2);
    _Float16* Bt3f = (_Float16*)alloc((size_t)64 * 512 * 2);
    _Float16* Bt0f = (_Float16*)alloc((size_t)128 * 64 * 2);
    char* R1 = alloc((size_t)N * 256 * 4);   // 51.2 MB
    char* R2 = alloc((size_t)N * 256 * 4);   // 51.2 MB
    char* R3 = alloc((size_t)N * 512 * 2);   // 51.2 MB (A512 fp16)
    (void)ws_size;

    // R1 phase 1: S128f [N,128] fp16 | A128f [N,128] fp16   phase 2: A256f
    _Float16*       S128f = (_Float16*)R1;
    _Float16*       A128f = (_Float16*)(R1 + (size_t)N * 128 * 2);
    _Float16*       A256f = (_Float16*)R1;
    // R2 phase 1: H2f [N,64] fp16   phase 2: G1f [N,256] fp16   phase 3: zbuf
    _Float16*       H2f  = (_Float16*)R2;
    _Float16*       G1f  = (_Float16*)R2;
    _Float16*       zbuf = (_Float16*)R2;
    // R3: A512f fp16 [N,512]
    _Float16*       A512f = (_Float16*)R3;

    // ---- degree + CSR + weight prep ----
    hipMemsetAsync(counts, 0, (size_t)N * 4, stream);
    hist_kernel<<<(E + 255) / 256, 256, 0, stream>>>(dst, counts, E);
    scan1_kernel<<<NB, 256, 0, stream>>>(counts, bsum, N);
    scan2_kernel<<<1, 256, 0, stream>>>(bsum, bsumx, offsets, NB, N);
    scan3_kernel<<<NB, 256, 0, stream>>>(counts, bsumx, offsets, cursor, dinv, N);
    fill_kernel<<<(E + 255) / 256, 256, 0, stream>>>(src, dst, dinv, cursor, edges, E);
    prepw_kernel<<<(204800 + 255) / 256, 256, 0, stream>>>(
        g1w, g2w, g3w, w3, Bt1f, Bt2f, Bt3f, Bt0f);

    const int MB = (N + 127) / 128;     // 391 row-blocks (BM=128)
    const int MB8 = (MB + 7) & ~7;      // 392 (pad to 8 for swizzle)
    const int MB64 = (N + 63) / 64;     // 782 row-blocks (BM=64)

    // ---- MLP: x -> h2 fp16 (fused), h2 -> h3 fp16 (f16 MFMA, K=64) ----
    mlp12_kernel<<<NB, 256, 0, stream>>>(x, w1, b1, w2, b2, H2f, N);
    {   dim3 grid(1, MB);
        gemm_f16_kernel<128, 128, 4, 2, 2, 4, 4, 0, false><<<grid, 256, 0, stream>>>(
            H2f, Bt0f, b3, S128f, N, 64, 128);
    }

    // ---- GCN1: agg@128 -> f16 MFMA 128->256 swiz2 ----
    agg_f16_kernel<128><<<((size_t)N * 16 + 255) / 256, 256, 0, stream>>>(
        S128f, offsets, edges, dinv, A128f, N);
    gemm_f16_kernel<128, 128, 4, 2, 2, 4, 4, 2, false><<<2 * MB8, 256, 0, stream>>>(
        A128f, Bt1f, g1b, G1f, N, 128, 256);

    // ---- GCN2: agg@256 -> f16 MFMA 256->512 swiz4 ----
    agg_f16_kernel<256><<<((size_t)N * 32 + 255) / 256, 256, 0, stream>>>(
        G1f, offsets, edges, dinv, A256f, N);
    gemm_f16_kernel<128, 128, 4, 2, 2, 4, 4, 4, false><<<4 * MB8, 256, 0, stream>>>(
        A256f, Bt2f, g2b, A512f, N, 256, 512);

    // ---- GCN3: f16 MFMA 512->64 BM=64 (raw fp16 out) -> agg + softmax ----
    {   dim3 grid(1, MB64);
        gemm_f16_kernel<64, 64, 4, 4, 1, 1, 4, 0, true><<<grid, 256, 0, stream>>>(
            A512f, Bt3f, nullptr, zbuf, N, 512, 64);
    }
    agg50_softmax_kernel<<<(N + 3) / 4, 256, 0, stream>>>(
        zbuf, offsets, edges, dinv, g3b, out, N);
}